// Round 1
// 289.334 us; speedup vs baseline: 1.0527x; 1.0527x over previous
//
#include <hip/hip_runtime.h>
#include <hip/hip_fp16.h>
#include <cstdint>

// Dims fixed: B=16, LQ=2048, EMB1=1024, EMB2=768, HDIM=1024, NHEAD=16, dh=64
//
// Algebra: out[b,l,h*64+d] = sigmoid(att[b,l,h]) * v[b,h*64+d]
//   att[b,l,h] = sum_e emb1[b,l,e] * Wqk[b,h,e] + attb[b,h]
//   Wqk[b,h,e] = sum_d k[b,h*64+d] * Wq[h*64+d, e]     (stored fp16)
//   attb[b,h]  = sum_d bq[h*64+d] * k[b,h*64+d]
//   k[b,:] = emb2[b,:] @ Wk^T + bk ;  v likewise.
//
// ws layout (bytes):
//   k    [16][1024] f32  @ 0       (65536)
//   v    [16][1024] f32  @ 65536   (65536)
//   attb [16][16]   f32  @ 131072  (1024)
//   wqk  [16][16][1024] fp16 @ 132096 (524288)

typedef float f4v __attribute__((ext_vector_type(4)));

// ---------------- Kernel A: k, v = emb2 @ W^T + bias (fp32) ----------------
// grid (256, 2): x = h-tile of 4, y = kind (0=K, 1=V). 256 threads.
// No LDS staging of emb2 (48 KB, L1/L2-resident). 4-way e-split + LDS reduce.
__global__ __launch_bounds__(256) void kv_kernel(
    const float* __restrict__ emb2, const float* __restrict__ Wk,
    const float* __restrict__ bk,   const float* __restrict__ Wv,
    const float* __restrict__ bv,   float* __restrict__ ws)
{
    const int kind  = blockIdx.y;
    const int htile = blockIdx.x;
    const float* W    = kind ? Wv : Wk;
    const float* bias = kind ? bv : bk;
    float* outp = ws + (kind ? 16384 : 0);

    const int t  = threadIdx.x;
    const int es = t >> 6;            // e-quarter 0..3
    const int hl = (t >> 4) & 3;      // head-in-tile 0..3
    const int b  = t & 15;            // batch 0..15
    const int h  = htile * 4 + hl;

    const float4* W4 = (const float4*)(W + (size_t)h * 768) + es * 48;
    const float4* E4 = (const float4*)(emb2 + (size_t)b * 768) + es * 48;

    float acc = 0.f;
    #pragma unroll 8
    for (int j = 0; j < 48; ++j) {
        float4 w = W4[j];
        float4 a = E4[j];
        acc += w.x * a.x + w.y * a.y + w.z * a.z + w.w * a.w;
    }

    __shared__ float red[256];
    red[t] = acc;
    __syncthreads();
    if (t < 64) {
        float s = red[t] + red[t + 64] + red[t + 128] + red[t + 192] + bias[h];
        outp[b * 1024 + h] = s;
    }
}

// ---------------- Kernel B: fold Wqk (fp16) + att bias ----------------
// grid (16, 16): x = h, y = b. 256 threads, thread owns 4 e-cols (float4 loads).
__global__ __launch_bounds__(256) void fold_kernel(
    const float* __restrict__ Wq, const float* __restrict__ bq,
    float* __restrict__ ws)
{
    const int h = blockIdx.x;
    const int b = blockIdx.y;
    const float* kvec = ws;                           // [16][1024]
    float* attb = ws + 32768;
    __half* wqk = (__half*)((char*)ws + 132096);

    const int t = threadIdx.x;
    __shared__ float kk[64];
    if (t < 64) {
        float kvl = kvec[b * 1024 + h * 64 + t];
        kk[t] = kvl;
        float s = kvl * bq[h * 64 + t];               // attb via wave reduce
        s += __shfl_xor(s, 1);  s += __shfl_xor(s, 2);
        s += __shfl_xor(s, 4);  s += __shfl_xor(s, 8);
        s += __shfl_xor(s, 16); s += __shfl_xor(s, 32);
        if (t == 0) attb[b * 16 + h] = s;
    }
    __syncthreads();

    float4 acc = make_float4(0.f, 0.f, 0.f, 0.f);
    const float4* Wrow = (const float4*)(Wq + (size_t)(h * 64) * 1024) + t;
    #pragma unroll 8
    for (int d = 0; d < 64; ++d) {
        float4 w = Wrow[(size_t)d * 256];             // 1 KB/wave-instr, coalesced
        float kd = kk[d];                             // wave-uniform broadcast
        acc.x += kd * w.x; acc.y += kd * w.y;
        acc.z += kd * w.z; acc.w += kd * w.w;
    }
    union { __half2 h2[2]; uint2 u; } pk;
    pk.h2[0] = __floats2half2_rn(acc.x, acc.y);
    pk.h2[1] = __floats2half2_rn(acc.z, acc.w);
    *(uint2*)(wqk + (size_t)(b * 16 + h) * 1024 + t * 4) = pk.u;
}

// ---------------- Kernel C: att + sigmoid gate + out (streaming) ----------
// grid (64, 16): x = 32-row block, y = batch. 256 threads = 4 waves.
// Wave w owns heads 4w..4w+3 with weights REGISTER-RESIDENT (fp16->f32 once,
// 64 VGPR). Each wave reads the full emb1 row (4x L1-absorbed amplification),
// computes 4 partial dots (64 FMA), butterfly-splits 4 heads over lane bits
// 0-1 (3 shuffles), reduces over lane bits 2-5 (4 shuffles), and writes its
// 256-col output slice [w*256, w*256+256) with non-temporal float4 stores.
// Next-row emb1 is prefetched into registers (software pipeline). No LDS.
__global__ __launch_bounds__(256, 3) void att_kernel(
    const float* __restrict__ emb1, const float* __restrict__ ws,
    float* __restrict__ out)
{
    const int bx = blockIdx.x;
    const int b  = blockIdx.y;
    const int t    = threadIdx.x;
    const int w    = t >> 6;
    const int lane = t & 63;

    const float*  vvec = ws + 16384 + b * 1024;
    const float*  attb = ws + 32768 + b * 16;
    const __half* wqk  = (const __half*)((const char*)ws + 132096) + (size_t)b * 16384;

    // Register-resident weights: 4 heads x 4 segs x float4 (cols seg*256+lane*4)
    float4 wf[4][4];
    #pragma unroll
    for (int hh = 0; hh < 4; ++hh) {
        const __half* wrow = wqk + (w * 4 + hh) * 1024;
        #pragma unroll
        for (int s = 0; s < 4; ++s) {
            const __half2* p = (const __half2*)(wrow + s * 256 + lane * 4);
            float2 lo = __half22float2(p[0]);
            float2 hi = __half22float2(p[1]);
            wf[hh][s] = make_float4(lo.x, lo.y, hi.x, hi.y);
        }
    }

    // After butterfly, lane owns local head hloc = bitrev2(lane&3).
    const int   hloc   = ((lane & 1) << 1) | ((lane >> 1) & 1);
    const float attb_l = attb[w * 4 + hloc];
    // For the write, lane needs gate of local head (lane>>4)&3 -> source lane:
    const int   gsrc   = ((lane >> 5) & 1) | (((lane >> 4) & 1) << 1);

    const float4 vv = *(const float4*)(vvec + w * 256 + lane * 4);

    const int row0 = bx * 32;
    const float* Abase = emb1 + ((size_t)b * 2048 + row0) * 1024 + lane * 4;
    float*       Obase = out  + ((size_t)b * 2048 + row0) * 1024 + w * 256 + lane * 4;

    float4 a[4], an[4];
    #pragma unroll
    for (int s = 0; s < 4; ++s) a[s] = *(const float4*)(Abase + s * 256);

    for (int r = 0; r < 32; ++r) {
        if (r < 31) {                                  // prefetch next row
            const float* An = Abase + (size_t)(r + 1) * 1024;
            #pragma unroll
            for (int s = 0; s < 4; ++s) an[s] = *(const float4*)(An + s * 256);
        }

        float acc[4] = {0.f, 0.f, 0.f, 0.f};
        #pragma unroll
        for (int s = 0; s < 4; ++s) {
            float4 as = a[s];
            #pragma unroll
            for (int hh = 0; hh < 4; ++hh) {
                float4 ww = wf[hh][s];
                acc[hh] += ww.x * as.x + ww.y * as.y + ww.z * as.z + ww.w * as.w;
            }
        }

        // butterfly: split 4 heads over lane bits 0-1
        {   // m=1: keep 2 heads by lane bit0
            const bool hi = lane & 1;
            #pragma unroll
            for (int i = 0; i < 2; ++i) {
                float send = hi ? acc[i] : acc[i + 2];
                float keep = hi ? acc[i + 2] : acc[i];
                acc[i] = keep + __shfl_xor(send, 1);
            }
        }
        float r0;
        {   // m=2
            const bool hi = lane & 2;
            float send = hi ? acc[0] : acc[1];
            float keep = hi ? acc[1] : acc[0];
            r0 = keep + __shfl_xor(send, 2);
        }
        r0 += __shfl_xor(r0, 4);
        r0 += __shfl_xor(r0, 8);
        r0 += __shfl_xor(r0, 16);
        r0 += __shfl_xor(r0, 32);

        const float att  = r0 + attb_l;
        const float gate = 1.0f / (1.0f + __expf(-att));
        const float g    = __shfl(gate, gsrc);

        f4v o;
        o.x = g * vv.x; o.y = g * vv.y; o.z = g * vv.z; o.w = g * vv.w;
        __builtin_nontemporal_store(o, (f4v*)(Obase + (size_t)r * 1024));

        if (r < 31) {
            #pragma unroll
            for (int s = 0; s < 4; ++s) a[s] = an[s];
        }
    }
}

extern "C" void kernel_launch(void* const* d_in, const int* in_sizes, int n_in,
                              void* d_out, int out_size, void* d_ws, size_t ws_size,
                              hipStream_t stream) {
    const float* emb1 = (const float*)d_in[0];
    const float* emb2 = (const float*)d_in[1];
    const float* Wq   = (const float*)d_in[2];
    const float* bq   = (const float*)d_in[3];
    const float* Wk   = (const float*)d_in[4];
    const float* bk   = (const float*)d_in[5];
    const float* Wv   = (const float*)d_in[6];
    const float* bv   = (const float*)d_in[7];
    float* out = (float*)d_out;
    float* ws  = (float*)d_ws;

    kv_kernel  <<<dim3(256, 2), 256, 0, stream>>>(emb2, Wk, bk, Wv, bv, ws);
    fold_kernel<<<dim3(16, 16), 256, 0, stream>>>(Wq, bq, ws);
    att_kernel <<<dim3(64, 16), 256, 0, stream>>>(emb1, ws, out);
}

// Round 2
// 288.795 us; speedup vs baseline: 1.0547x; 1.0019x over previous
//
#include <hip/hip_runtime.h>
#include <hip/hip_fp16.h>
#include <cstdint>

// Dims fixed: B=16, LQ=2048, EMB1=1024, EMB2=768, HDIM=1024, NHEAD=16, dh=64
//
// Algebra: out[b,l,h*64+d] = sigmoid(att[b,l,h]) * v[b,h*64+d]
//   att[b,l,h] = sum_e emb1[b,l,e] * Wqk[b,h,e] + attb[b,h]
//   Wqk[b,h,e] = sum_d k[b,h*64+d] * Wq[h*64+d, e]     (stored fp16)
//   attb[b,h]  = sum_d bq[h*64+d] * k[b,h*64+d]
//   k[b,:] = emb2[b,:] @ Wk^T + bk ;  v likewise.
//
// ws layout (bytes):
//   k    [16][1024] f32  @ 0       (65536)
//   v    [16][1024] f32  @ 65536   (65536)
//   attb [16][16]   f32  @ 131072  (1024)
//   wqk  [16][16][1024] fp16 @ 132096 (524288)

typedef float f4v __attribute__((ext_vector_type(4)));
typedef _Float16 h2v __attribute__((ext_vector_type(2)));

// ---------------- Kernel A: k, v = emb2 @ W^T + bias (fp32) ----------------
// grid (256, 2): x = h-tile of 4, y = kind (0=K, 1=V). 256 threads.
__global__ __launch_bounds__(256) void kv_kernel(
    const float* __restrict__ emb2, const float* __restrict__ Wk,
    const float* __restrict__ bk,   const float* __restrict__ Wv,
    const float* __restrict__ bv,   float* __restrict__ ws)
{
    const int kind  = blockIdx.y;
    const int htile = blockIdx.x;
    const float* W    = kind ? Wv : Wk;
    const float* bias = kind ? bv : bk;
    float* outp = ws + (kind ? 16384 : 0);

    const int t  = threadIdx.x;
    const int es = t >> 6;            // e-quarter 0..3
    const int hl = (t >> 4) & 3;      // head-in-tile 0..3
    const int b  = t & 15;            // batch 0..15
    const int h  = htile * 4 + hl;

    const float4* W4 = (const float4*)(W + (size_t)h * 768) + es * 48;
    const float4* E4 = (const float4*)(emb2 + (size_t)b * 768) + es * 48;

    float acc = 0.f;
    #pragma unroll 8
    for (int j = 0; j < 48; ++j) {
        float4 w = W4[j];
        float4 a = E4[j];
        acc += w.x * a.x + w.y * a.y + w.z * a.z + w.w * a.w;
    }

    __shared__ float red[256];
    red[t] = acc;
    __syncthreads();
    if (t < 64) {
        float s = red[t] + red[t + 64] + red[t + 128] + red[t + 192] + bias[h];
        outp[b * 1024 + h] = s;
    }
}

// ---------------- Kernel B: fold Wqk (fp16) + att bias ----------------
// grid (16, 16): x = h, y = b. 256 threads, thread owns 4 e-cols (float4 loads).
__global__ __launch_bounds__(256) void fold_kernel(
    const float* __restrict__ Wq, const float* __restrict__ bq,
    float* __restrict__ ws)
{
    const int h = blockIdx.x;
    const int b = blockIdx.y;
    const float* kvec = ws;                           // [16][1024]
    float* attb = ws + 32768;
    __half* wqk = (__half*)((char*)ws + 132096);

    const int t = threadIdx.x;
    __shared__ float kk[64];
    if (t < 64) {
        float kvl = kvec[b * 1024 + h * 64 + t];
        kk[t] = kvl;
        float s = kvl * bq[h * 64 + t];               // attb via wave reduce
        s += __shfl_xor(s, 1);  s += __shfl_xor(s, 2);
        s += __shfl_xor(s, 4);  s += __shfl_xor(s, 8);
        s += __shfl_xor(s, 16); s += __shfl_xor(s, 32);
        if (t == 0) attb[b * 16 + h] = s;
    }
    __syncthreads();

    float4 acc = make_float4(0.f, 0.f, 0.f, 0.f);
    const float4* Wrow = (const float4*)(Wq + (size_t)(h * 64) * 1024) + t;
    #pragma unroll 8
    for (int d = 0; d < 64; ++d) {
        float4 w = Wrow[(size_t)d * 256];             // 1 KB/wave-instr, coalesced
        float kd = kk[d];                             // wave-uniform broadcast
        acc.x += kd * w.x; acc.y += kd * w.y;
        acc.z += kd * w.z; acc.w += kd * w.w;
    }
    union { __half2 h2[2]; uint2 u; } pk;
    pk.h2[0] = __floats2half2_rn(acc.x, acc.y);
    pk.h2[1] = __floats2half2_rn(acc.z, acc.w);
    *(uint2*)(wqk + (size_t)(b * 16 + h) * 1024 + t * 4) = pk.u;
}

// ---------------- Kernel C: att + sigmoid gate + out (streaming) ----------
// grid (128, 16): x = 16-row block, y = batch. 256 threads = 4 waves.
// Wave w owns heads 4w..4w+3; weights stay PACKED f16 in 32 VGPRs and the
// dot uses v_dot2_f32_f16 (f32 accumulate). emb1 row is converted f32->f16
// once per row (16 cvt + 8 pack), then 32 fdot2 per row -- no per-row weight
// conversion (round-1's VGPR=64 showed the compiler re-materialized 64 cvt
// per row). 16-row blocks double the grid (2048 blocks) for ~6 waves/SIMD.
// Butterfly splits 4 heads over lane bits 0-1 (3 shuffles) then xor-reduce.
// No LDS. Non-temporal float4 stores.
__global__ __launch_bounds__(256, 6) void att_kernel(
    const float* __restrict__ emb1, const float* __restrict__ ws,
    float* __restrict__ out)
{
    const int bx = blockIdx.x;
    const int b  = blockIdx.y;
    const int t    = threadIdx.x;
    const int w    = t >> 6;
    const int lane = t & 63;

    const float*  vvec = ws + 16384 + b * 1024;
    const float*  attb = ws + 32768 + b * 16;
    const __half* wqk  = (const __half*)((const char*)ws + 132096) + (size_t)b * 16384;

    // Packed weights: 4 heads x 4 segs x 2 half2  (cols seg*256 + lane*4 .. +3)
    h2v wh[4][4][2];
    #pragma unroll
    for (int hh = 0; hh < 4; ++hh) {
        const __half* wrow = wqk + (w * 4 + hh) * 1024;
        #pragma unroll
        for (int s = 0; s < 4; ++s) {
            const h2v* p = (const h2v*)(wrow + s * 256 + lane * 4);
            wh[hh][s][0] = p[0];
            wh[hh][s][1] = p[1];
        }
    }

    // After butterfly, lane owns local head hloc = bitrev2(lane&3).
    const int   hloc   = ((lane & 1) << 1) | ((lane >> 1) & 1);
    const float attb_l = attb[w * 4 + hloc];
    // For the write, lane needs gate of local head lane>>4 -> source lane:
    const int   gsrc   = ((lane >> 5) & 1) | (((lane >> 4) & 1) << 1);

    const float4 vv = *(const float4*)(vvec + w * 256 + lane * 4);

    const int row0 = bx * 16;
    const float* Abase = emb1 + ((size_t)b * 2048 + row0) * 1024 + lane * 4;
    float*       Obase = out  + ((size_t)b * 2048 + row0) * 1024 + w * 256 + lane * 4;

    float4 a[4], an[4];
    #pragma unroll
    for (int s = 0; s < 4; ++s) a[s] = *(const float4*)(Abase + s * 256);

    for (int r = 0; r < 16; ++r) {
        if (r < 15) {                                  // prefetch next row
            const float* An = Abase + (size_t)(r + 1) * 1024;
            #pragma unroll
            for (int s = 0; s < 4; ++s) an[s] = *(const float4*)(An + s * 256);
        }

        // convert this row to packed f16 once (RN per element)
        h2v ah[4][2];
        #pragma unroll
        for (int s = 0; s < 4; ++s) {
            ah[s][0] = h2v{(_Float16)a[s].x, (_Float16)a[s].y};
            ah[s][1] = h2v{(_Float16)a[s].z, (_Float16)a[s].w};
        }

        float acc[4] = {0.f, 0.f, 0.f, 0.f};
        #pragma unroll
        for (int s = 0; s < 4; ++s) {
            #pragma unroll
            for (int hh = 0; hh < 4; ++hh) {
                acc[hh] = __builtin_amdgcn_fdot2(wh[hh][s][0], ah[s][0], acc[hh], false);
                acc[hh] = __builtin_amdgcn_fdot2(wh[hh][s][1], ah[s][1], acc[hh], false);
            }
        }

        // butterfly: split 4 heads over lane bits 0-1
        {   // m=1: keep 2 heads by lane bit0
            const bool hi = lane & 1;
            #pragma unroll
            for (int i = 0; i < 2; ++i) {
                float send = hi ? acc[i] : acc[i + 2];
                float keep = hi ? acc[i + 2] : acc[i];
                acc[i] = keep + __shfl_xor(send, 1);
            }
        }
        float r0;
        {   // m=2
            const bool hi = lane & 2;
            float send = hi ? acc[0] : acc[1];
            float keep = hi ? acc[1] : acc[0];
            r0 = keep + __shfl_xor(send, 2);
        }
        r0 += __shfl_xor(r0, 4);
        r0 += __shfl_xor(r0, 8);
        r0 += __shfl_xor(r0, 16);
        r0 += __shfl_xor(r0, 32);

        const float att  = r0 + attb_l;
        const float gate = 1.0f / (1.0f + __expf(-att));
        const float g    = __shfl(gate, gsrc);

        f4v o;
        o.x = g * vv.x; o.y = g * vv.y; o.z = g * vv.z; o.w = g * vv.w;
        __builtin_nontemporal_store(o, (f4v*)(Obase + (size_t)r * 1024));

        if (r < 15) {
            #pragma unroll
            for (int s = 0; s < 4; ++s) a[s] = an[s];
        }
    }
}

extern "C" void kernel_launch(void* const* d_in, const int* in_sizes, int n_in,
                              void* d_out, int out_size, void* d_ws, size_t ws_size,
                              hipStream_t stream) {
    const float* emb1 = (const float*)d_in[0];
    const float* emb2 = (const float*)d_in[1];
    const float* Wq   = (const float*)d_in[2];
    const float* bq   = (const float*)d_in[3];
    const float* Wk   = (const float*)d_in[4];
    const float* bk   = (const float*)d_in[5];
    const float* Wv   = (const float*)d_in[6];
    const float* bv   = (const float*)d_in[7];
    float* out = (float*)d_out;
    float* ws  = (float*)d_ws;

    kv_kernel  <<<dim3(256, 2),  256, 0, stream>>>(emb2, Wk, bk, Wv, bv, ws);
    fold_kernel<<<dim3(16, 16),  256, 0, stream>>>(Wq, bq, ws);
    att_kernel <<<dim3(128, 16), 256, 0, stream>>>(emb1, ws, out);
}

// Round 3
// 285.272 us; speedup vs baseline: 1.0677x; 1.0124x over previous
//
#include <hip/hip_runtime.h>
#include <hip/hip_fp16.h>
#include <cstdint>

// Dims fixed: B=16, LQ=2048, EMB1=1024, EMB2=768, HDIM=1024, NHEAD=16, dh=64
//
// Algebra: out[b,l,h*64+d] = sigmoid(att[b,l,h]) * v[b,h*64+d]
//   att[b,l,h] = sum_e emb1[b,l,e] * Wqk[b,h,e] + attb[b,h]
//   Wqk[b,h,e] = sum_d k[b,h*64+d] * Wq[h*64+d, e]     (stored fp16)
//   attb[b,h]  = sum_d bq[h*64+d] * k[b,h*64+d]
//   k[b,:] = emb2[b,:] @ Wk^T + bk ;  v likewise.
//
// ws layout (bytes):
//   k    [16][1024] f32  @ 0       (65536)
//   v    [16][1024] f32  @ 65536   (65536)
//   attb [16][16]   f32  @ 131072  (1024)
//   wqk  [16][16][1024] fp16 @ 132096 (524288)

typedef float    f4v __attribute__((ext_vector_type(4)));
typedef _Float16 h8v __attribute__((ext_vector_type(8)));

// ---------------- Kernel A: k, v = emb2 @ W^T + bias (fp32) ----------------
// grid (256, 2): x = h-tile of 4, y = kind (0=K, 1=V). 256 threads.
__global__ __launch_bounds__(256) void kv_kernel(
    const float* __restrict__ emb2, const float* __restrict__ Wk,
    const float* __restrict__ bk,   const float* __restrict__ Wv,
    const float* __restrict__ bv,   float* __restrict__ ws)
{
    const int kind  = blockIdx.y;
    const int htile = blockIdx.x;
    const float* W    = kind ? Wv : Wk;
    const float* bias = kind ? bv : bk;
    float* outp = ws + (kind ? 16384 : 0);

    const int t  = threadIdx.x;
    const int es = t >> 6;            // e-quarter 0..3
    const int hl = (t >> 4) & 3;      // head-in-tile 0..3
    const int b  = t & 15;            // batch 0..15
    const int h  = htile * 4 + hl;

    const float4* W4 = (const float4*)(W + (size_t)h * 768) + es * 48;
    const float4* E4 = (const float4*)(emb2 + (size_t)b * 768) + es * 48;

    float acc = 0.f;
    #pragma unroll 8
    for (int j = 0; j < 48; ++j) {
        float4 w = W4[j];
        float4 a = E4[j];
        acc += w.x * a.x + w.y * a.y + w.z * a.z + w.w * a.w;
    }

    __shared__ float red[256];
    red[t] = acc;
    __syncthreads();
    if (t < 64) {
        float s = red[t] + red[t + 64] + red[t + 128] + red[t + 192] + bias[h];
        outp[b * 1024 + h] = s;
    }
}

// ---------------- Kernel B: fold Wqk (fp16) + att bias ----------------
// grid (16, 16): x = h, y = b. 256 threads, thread owns 4 e-cols (float4 loads).
__global__ __launch_bounds__(256) void fold_kernel(
    const float* __restrict__ Wq, const float* __restrict__ bq,
    float* __restrict__ ws)
{
    const int h = blockIdx.x;
    const int b = blockIdx.y;
    const float* kvec = ws;                           // [16][1024]
    float* attb = ws + 32768;
    __half* wqk = (__half*)((char*)ws + 132096);

    const int t = threadIdx.x;
    __shared__ float kk[64];
    if (t < 64) {
        float kvl = kvec[b * 1024 + h * 64 + t];
        kk[t] = kvl;
        float s = kvl * bq[h * 64 + t];               // attb via wave reduce
        s += __shfl_xor(s, 1);  s += __shfl_xor(s, 2);
        s += __shfl_xor(s, 4);  s += __shfl_xor(s, 8);
        s += __shfl_xor(s, 16); s += __shfl_xor(s, 32);
        if (t == 0) attb[b * 16 + h] = s;
    }
    __syncthreads();

    float4 acc = make_float4(0.f, 0.f, 0.f, 0.f);
    const float4* Wrow = (const float4*)(Wq + (size_t)(h * 64) * 1024) + t;
    #pragma unroll 8
    for (int d = 0; d < 64; ++d) {
        float4 w = Wrow[(size_t)d * 256];             // 1 KB/wave-instr, coalesced
        float kd = kk[d];                             // wave-uniform broadcast
        acc.x += kd * w.x; acc.y += kd * w.y;
        acc.z += kd * w.z; acc.w += kd * w.w;
    }
    union { __half2 h2[2]; uint2 u; } pk;
    pk.h2[0] = __floats2half2_rn(acc.x, acc.y);
    pk.h2[1] = __floats2half2_rn(acc.z, acc.w);
    *(uint2*)(wqk + (size_t)(b * 16 + h) * 1024 + t * 4) = pk.u;
}

// ---------------- Kernel C: att via MFMA + sigmoid gate + out -------------
// grid (64, 16): x = 32-row block (2 waves x 16-row MFMA tile), y = batch.
// 128 threads = 2 waves, each wave owns one independent M=16 tile.
// att[16 rows][16 heads] = emb1_tile[16x1024] @ wqk_b^T via 32x
// mfma_f32_16x16x32_f16 (K=1024). A-frag: lane holds emb1[row=lane&15]
// [k=(lane>>4)*8..+7] converted f32->f16 in-reg (same precision as round-2's
// fdot2 path). B-frag: wqk[head=lane&15][same k] loaded 16B/lane (L2-hot).
// C/D: acc[j] = att[row=(lane>>4)*4+j][head=lane&15]  (m89-verified layout).
// No cross-lane shuffles, no reduction tree; emb1 read exactly once.
// Epilogue: gates via padded LDS tile (broadcast reads), coalesced
// non-temporal float4 stores.
__global__ __launch_bounds__(128) void att_kernel(
    const float* __restrict__ emb1, const float* __restrict__ ws,
    float* __restrict__ out)
{
    const int b    = blockIdx.y;
    const int t    = threadIdx.x;
    const int w    = t >> 6;
    const int lane = t & 63;
    const int q    = lane >> 4;        // quarter 0..3
    const int m    = lane & 15;        // row-in-tile (A) / head (B,D)

    const int row0 = blockIdx.x * 32 + w * 16;

    const float*    vvec  = ws + 16384 + b * 1024;
    const float*    attbp = ws + 32768 + b * 16;
    const _Float16* wqk   = (const _Float16*)((const char*)ws + 132096)
                          + (size_t)b * 16384;

    const float*    Ap = emb1 + ((size_t)b * 2048 + row0 + m) * 1024 + q * 8;
    const _Float16* Bp = wqk + m * 1024 + q * 8;

    f4v acc = {0.f, 0.f, 0.f, 0.f};

    // 1-deep software pipeline over 32 K-chunks of 32
    f4v a0 = *(const f4v*)(Ap);
    f4v a1 = *(const f4v*)(Ap + 4);
    h8v bf = *(const h8v*)(Bp);

    for (int c = 0; c < 32; ++c) {
        const int cn = (c < 31) ? c + 1 : 31;       // last iter: reload (L1-hot)
        const float* An = Ap + cn * 32;
        f4v a0n = *(const f4v*)(An);
        f4v a1n = *(const f4v*)(An + 4);
        h8v bfn = *(const h8v*)(Bp + cn * 32);

        h8v af;
        af[0] = (_Float16)a0[0]; af[1] = (_Float16)a0[1];
        af[2] = (_Float16)a0[2]; af[3] = (_Float16)a0[3];
        af[4] = (_Float16)a1[0]; af[5] = (_Float16)a1[1];
        af[6] = (_Float16)a1[2]; af[7] = (_Float16)a1[3];

        acc = __builtin_amdgcn_mfma_f32_16x16x32_f16(af, bf, acc, 0, 0, 0);

        a0 = a0n; a1 = a1n; bf = bfn;
    }

    // gates -> LDS (padded: row stride 17 words, broadcast-read pattern)
    __shared__ float gl[2][16 * 17];
    float* g = gl[w];
    const float attb_l = attbp[m];
    #pragma unroll
    for (int j = 0; j < 4; ++j) {
        float att  = acc[j] + attb_l;                 // row q*4+j, head m
        float gate = 1.0f / (1.0f + __expf(-att));
        g[(q * 4 + j) * 17 + m] = gate;
    }
    __syncthreads();

    f4v vv[4];
    #pragma unroll
    for (int s = 0; s < 4; ++s)
        vv[s] = *(const f4v*)(vvec + s * 256 + lane * 4);

    float* Ob = out + ((size_t)b * 2048 + row0) * 1024 + lane * 4;
    #pragma unroll
    for (int r = 0; r < 16; ++r) {
        #pragma unroll
        for (int s = 0; s < 4; ++s) {
            // col = s*256 + lane*4  ->  head = s*4 + q
            float gg = g[r * 17 + s * 4 + q];         // broadcast within quarter
            f4v o = gg * vv[s];
            __builtin_nontemporal_store(o, (f4v*)(Ob + (size_t)r * 1024 + s * 256));
        }
    }
}

extern "C" void kernel_launch(void* const* d_in, const int* in_sizes, int n_in,
                              void* d_out, int out_size, void* d_ws, size_t ws_size,
                              hipStream_t stream) {
    const float* emb1 = (const float*)d_in[0];
    const float* emb2 = (const float*)d_in[1];
    const float* Wq   = (const float*)d_in[2];
    const float* bq   = (const float*)d_in[3];
    const float* Wk   = (const float*)d_in[4];
    const float* bk   = (const float*)d_in[5];
    const float* Wv   = (const float*)d_in[6];
    const float* bv   = (const float*)d_in[7];
    float* out = (float*)d_out;
    float* ws  = (float*)d_ws;

    kv_kernel  <<<dim3(256, 2), 256, 0, stream>>>(emb2, Wk, bk, Wv, bv, ws);
    fold_kernel<<<dim3(16, 16), 256, 0, stream>>>(Wq, bq, ws);
    att_kernel <<<dim3(64, 16), 128, 0, stream>>>(emb1, ws, out);
}

// Round 4
// 276.399 us; speedup vs baseline: 1.1020x; 1.0321x over previous
//
#include <hip/hip_runtime.h>
#include <hip/hip_fp16.h>
#include <cstdint>

// Dims fixed: B=16, LQ=2048, EMB1=1024, EMB2=768, HDIM=1024, NHEAD=16, dh=64
//
// Algebra: out[b,l,h*64+d] = sigmoid(att[b,l,h]) * v[b,h*64+d]
//   att[b,l,h] = sum_e emb1[b,l,e] * Wqk[b,h,e] + attb[b,h]
//   Wqk[b,h,e] = sum_d k[b,h*64+d] * Wq[h*64+d, e]     (stored fp16)
//   attb[b,h]  = sum_d bq[h*64+d] * k[b,h*64+d]
//   k[b,:] = emb2[b,:] @ Wk^T + bk ;  v likewise.
//
// ws layout (bytes):
//   k    [16][1024] f32  @ 0       (65536)
//   v    [16][1024] f32  @ 65536   (65536)
//   attb [16][16]   f32  @ 131072  (1024)
//   wqk  [16][16][1024] fp16 @ 132096 (524288)

typedef float    f4v __attribute__((ext_vector_type(4)));
typedef _Float16 h8v __attribute__((ext_vector_type(8)));

// ---------------- Kernel A: k, v = emb2 @ W^T + bias (fp32) ----------------
// grid (256, 2): x = h-tile of 4, y = kind (0=K, 1=V). 256 threads.
__global__ __launch_bounds__(256) void kv_kernel(
    const float* __restrict__ emb2, const float* __restrict__ Wk,
    const float* __restrict__ bk,   const float* __restrict__ Wv,
    const float* __restrict__ bv,   float* __restrict__ ws)
{
    const int kind  = blockIdx.y;
    const int htile = blockIdx.x;
    const float* W    = kind ? Wv : Wk;
    const float* bias = kind ? bv : bk;
    float* outp = ws + (kind ? 16384 : 0);

    const int t  = threadIdx.x;
    const int es = t >> 6;            // e-quarter 0..3
    const int hl = (t >> 4) & 3;      // head-in-tile 0..3
    const int b  = t & 15;            // batch 0..15
    const int h  = htile * 4 + hl;

    const float4* W4 = (const float4*)(W + (size_t)h * 768) + es * 48;
    const float4* E4 = (const float4*)(emb2 + (size_t)b * 768) + es * 48;

    float acc = 0.f;
    #pragma unroll 8
    for (int j = 0; j < 48; ++j) {
        float4 w = W4[j];
        float4 a = E4[j];
        acc += w.x * a.x + w.y * a.y + w.z * a.z + w.w * a.w;
    }

    __shared__ float red[256];
    red[t] = acc;
    __syncthreads();
    if (t < 64) {
        float s = red[t] + red[t + 64] + red[t + 128] + red[t + 192] + bias[h];
        outp[b * 1024 + h] = s;
    }
}

// ---------------- Kernel B: fold Wqk (fp16) + att bias ----------------
// grid (16, 16): x = h, y = b. 256 threads, thread owns 4 e-cols (float4 loads).
__global__ __launch_bounds__(256) void fold_kernel(
    const float* __restrict__ Wq, const float* __restrict__ bq,
    float* __restrict__ ws)
{
    const int h = blockIdx.x;
    const int b = blockIdx.y;
    const float* kvec = ws;                           // [16][1024]
    float* attb = ws + 32768;
    __half* wqk = (__half*)((char*)ws + 132096);

    const int t = threadIdx.x;
    __shared__ float kk[64];
    if (t < 64) {
        float kvl = kvec[b * 1024 + h * 64 + t];
        kk[t] = kvl;
        float s = kvl * bq[h * 64 + t];               // attb via wave reduce
        s += __shfl_xor(s, 1);  s += __shfl_xor(s, 2);
        s += __shfl_xor(s, 4);  s += __shfl_xor(s, 8);
        s += __shfl_xor(s, 16); s += __shfl_xor(s, 32);
        if (t == 0) attb[b * 16 + h] = s;
    }
    __syncthreads();

    float4 acc = make_float4(0.f, 0.f, 0.f, 0.f);
    const float4* Wrow = (const float4*)(Wq + (size_t)(h * 64) * 1024) + t;
    #pragma unroll 8
    for (int d = 0; d < 64; ++d) {
        float4 w = Wrow[(size_t)d * 256];             // 1 KB/wave-instr, coalesced
        float kd = kk[d];                             // wave-uniform broadcast
        acc.x += kd * w.x; acc.y += kd * w.y;
        acc.z += kd * w.z; acc.w += kd * w.w;
    }
    union { __half2 h2[2]; uint2 u; } pk;
    pk.h2[0] = __floats2half2_rn(acc.x, acc.y);
    pk.h2[1] = __floats2half2_rn(acc.z, acc.w);
    *(uint2*)(wqk + (size_t)(b * 16 + h) * 1024 + t * 4) = pk.u;
}

// ---------------- Kernel C: att via MFMA + sigmoid gate + out -------------
// grid (32, 16): x = 64-row block (4 waves x 16-row MFMA tile), y = batch.
// 256 threads = 4 waves; all 4 waves stream the SAME wqk B-fragments (L1 hits).
// att[16 rows][16 heads] = emb1_tile[16x1024] @ wqk_b^T via 32x
// mfma_f32_16x16x32_f16 (K=1024). Fragment mapping identical to round 3
// (verified: absmax unchanged).
//
// KEY CHANGE vs round 3 (VGPR=32 proved the compiler collapsed the 1-deep
// prefetch; every K-iter exposed full HBM latency): explicit 4-slot rotating
// register pipeline, prefetch distance 3, expressed via macros + a ROLLED
// outer loop (#pragma unroll 1) so the slots stay 4 physical register sets.
// Steady state: ~3 generations x 48B/lane in flight = ~9KB/wave, 8 waves/CU
// -> ~72KB/CU outstanding (need ~9KB/CU for 6.3 TB/s at ~375ns latency).
__global__ __launch_bounds__(256, 2) void att_kernel(
    const float* __restrict__ emb1, const float* __restrict__ ws,
    float* __restrict__ out)
{
    const int b    = blockIdx.y;
    const int t    = threadIdx.x;
    const int w    = t >> 6;
    const int lane = t & 63;
    const int q    = lane >> 4;        // quarter 0..3
    const int m    = lane & 15;        // row-in-tile (A) / head (B,D)

    const int row0 = blockIdx.x * 64 + w * 16;

    const float*    vvec  = ws + 16384 + b * 1024;
    const float*    attbp = ws + 32768 + b * 16;
    const _Float16* wqk   = (const _Float16*)((const char*)ws + 132096)
                          + (size_t)b * 16384;

    const float*    Ap = emb1 + ((size_t)b * 2048 + row0 + m) * 1024 + q * 8;
    const _Float16* Bp = wqk + m * 1024 + q * 8;

    f4v A0[4], A1[4];
    h8v Bf[4];
    f4v acc = {0.f, 0.f, 0.f, 0.f};

#define LOADA(S, C)                                                  \
    do {                                                             \
        const float* _ap = Ap + (C) * 32;                            \
        A0[S] = *(const f4v*)(_ap);                                  \
        A1[S] = *(const f4v*)(_ap + 4);                              \
        Bf[S] = *(const h8v*)(Bp + (C) * 32);                        \
    } while (0)

#define STEP(S)                                                      \
    do {                                                             \
        f4v _a0 = A0[S], _a1 = A1[S];                                \
        h8v _af;                                                     \
        _af[0] = (_Float16)_a0[0]; _af[1] = (_Float16)_a0[1];        \
        _af[2] = (_Float16)_a0[2]; _af[3] = (_Float16)_a0[3];        \
        _af[4] = (_Float16)_a1[0]; _af[5] = (_Float16)_a1[1];        \
        _af[6] = (_Float16)_a1[2]; _af[7] = (_Float16)_a1[3];        \
        acc = __builtin_amdgcn_mfma_f32_16x16x32_f16(_af, Bf[S], acc, 0, 0, 0); \
    } while (0)

    LOADA(0, 0); LOADA(1, 1); LOADA(2, 2);

    #pragma unroll 1
    for (int cb = 0; cb < 28; cb += 4) {
        LOADA(3, cb + 3); STEP(0);
        LOADA(0, cb + 4); STEP(1);
        LOADA(1, cb + 5); STEP(2);
        LOADA(2, cb + 6); STEP(3);
    }
    // slots now hold chunks 28,29,30 ; fetch 31 and drain
    LOADA(3, 31);
    STEP(0); STEP(1); STEP(2); STEP(3);

#undef LOADA
#undef STEP

    // gates -> LDS (padded: row stride 17 words, broadcast-read pattern)
    __shared__ float gl[4][16 * 17];
    float* g = gl[w];
    const float attb_l = attbp[m];
    #pragma unroll
    for (int j = 0; j < 4; ++j) {
        float att  = acc[j] + attb_l;                 // row q*4+j, head m
        float gate = 1.0f / (1.0f + __expf(-att));
        g[(q * 4 + j) * 17 + m] = gate;
    }
    __syncthreads();

    f4v vv[4];
    #pragma unroll
    for (int s = 0; s < 4; ++s)
        vv[s] = *(const f4v*)(vvec + s * 256 + lane * 4);

    float* Ob = out + ((size_t)b * 2048 + row0) * 1024 + lane * 4;
    #pragma unroll
    for (int r = 0; r < 16; ++r) {
        #pragma unroll
        for (int s = 0; s < 4; ++s) {
            // col = s*256 + lane*4  ->  head = s*4 + q
            float gg = g[r * 17 + s * 4 + q];         // broadcast within quarter
            f4v o = gg * vv[s];
            __builtin_nontemporal_store(o, (f4v*)(Ob + (size_t)r * 1024 + s * 256));
        }
    }
}

extern "C" void kernel_launch(void* const* d_in, const int* in_sizes, int n_in,
                              void* d_out, int out_size, void* d_ws, size_t ws_size,
                              hipStream_t stream) {
    const float* emb1 = (const float*)d_in[0];
    const float* emb2 = (const float*)d_in[1];
    const float* Wq   = (const float*)d_in[2];
    const float* bq   = (const float*)d_in[3];
    const float* Wk   = (const float*)d_in[4];
    const float* bk   = (const float*)d_in[5];
    const float* Wv   = (const float*)d_in[6];
    const float* bv   = (const float*)d_in[7];
    float* out = (float*)d_out;
    float* ws  = (float*)d_ws;

    kv_kernel  <<<dim3(256, 2), 256, 0, stream>>>(emb2, Wk, bk, Wv, bv, ws);
    fold_kernel<<<dim3(16, 16), 256, 0, stream>>>(Wq, bq, ws);
    att_kernel <<<dim3(32, 16), 256, 0, stream>>>(emb1, ws, out);
}

// Round 5
// 274.476 us; speedup vs baseline: 1.1097x; 1.0070x over previous
//
#include <hip/hip_runtime.h>
#include <hip/hip_fp16.h>
#include <cstdint>

// Dims fixed: B=16, LQ=2048, EMB1=1024, EMB2=768, HDIM=1024, NHEAD=16, dh=64
//
// Algebra: out[b,l,h*64+d] = sigmoid(att[b,l,h]) * v[b,h*64+d]
//   att[b,l,h] = sum_e emb1[b,l,e] * Wqk[b,h,e] + attb[b,h]
//   Wqk[b,h,e] = sum_d k[b,h*64+d] * Wq[h*64+d, e]     (stored fp16)
//   attb[b,h]  = sum_d bq[h*64+d] * k[b,h*64+d]
//   k[b,:] = emb2[b,:] @ Wk^T + bk ;  v likewise.
//
// ws layout (bytes):
//   k    [16][1024] f32  @ 0       (65536)
//   v    [16][1024] f32  @ 65536   (65536)
//   attb [16][16]   f32  @ 131072  (1024)
//   wqk  [16][16][1024] fp16 @ 132096 (524288)

typedef float    f4v __attribute__((ext_vector_type(4)));
typedef _Float16 h8v __attribute__((ext_vector_type(8)));

// ---------------- Kernel A: k, v = emb2 @ W^T + bias (fp32) ----------------
// grid (256, 2): x = h-tile of 4, y = kind (0=K, 1=V). 256 threads.
__global__ __launch_bounds__(256) void kv_kernel(
    const float* __restrict__ emb2, const float* __restrict__ Wk,
    const float* __restrict__ bk,   const float* __restrict__ Wv,
    const float* __restrict__ bv,   float* __restrict__ ws)
{
    const int kind  = blockIdx.y;
    const int htile = blockIdx.x;
    const float* W    = kind ? Wv : Wk;
    const float* bias = kind ? bv : bk;
    float* outp = ws + (kind ? 16384 : 0);

    const int t  = threadIdx.x;
    const int es = t >> 6;            // e-quarter 0..3
    const int hl = (t >> 4) & 3;      // head-in-tile 0..3
    const int b  = t & 15;            // batch 0..15
    const int h  = htile * 4 + hl;

    const float4* W4 = (const float4*)(W + (size_t)h * 768) + es * 48;
    const float4* E4 = (const float4*)(emb2 + (size_t)b * 768) + es * 48;

    float acc = 0.f;
    #pragma unroll 8
    for (int j = 0; j < 48; ++j) {
        float4 w = W4[j];
        float4 a = E4[j];
        acc += w.x * a.x + w.y * a.y + w.z * a.z + w.w * a.w;
    }

    __shared__ float red[256];
    red[t] = acc;
    __syncthreads();
    if (t < 64) {
        float s = red[t] + red[t + 64] + red[t + 128] + red[t + 192] + bias[h];
        outp[b * 1024 + h] = s;
    }
}

// ---------------- Kernel B: fold Wqk (fp16) + att bias ----------------
// grid (16, 16): x = h, y = b. 256 threads, thread owns 4 e-cols (float4 loads).
__global__ __launch_bounds__(256) void fold_kernel(
    const float* __restrict__ Wq, const float* __restrict__ bq,
    float* __restrict__ ws)
{
    const int h = blockIdx.x;
    const int b = blockIdx.y;
    const float* kvec = ws;                           // [16][1024]
    float* attb = ws + 32768;
    __half* wqk = (__half*)((char*)ws + 132096);

    const int t = threadIdx.x;
    __shared__ float kk[64];
    if (t < 64) {
        float kvl = kvec[b * 1024 + h * 64 + t];
        kk[t] = kvl;
        float s = kvl * bq[h * 64 + t];               // attb via wave reduce
        s += __shfl_xor(s, 1);  s += __shfl_xor(s, 2);
        s += __shfl_xor(s, 4);  s += __shfl_xor(s, 8);
        s += __shfl_xor(s, 16); s += __shfl_xor(s, 32);
        if (t == 0) attb[b * 16 + h] = s;
    }
    __syncthreads();

    float4 acc = make_float4(0.f, 0.f, 0.f, 0.f);
    const float4* Wrow = (const float4*)(Wq + (size_t)(h * 64) * 1024) + t;
    #pragma unroll 8
    for (int d = 0; d < 64; ++d) {
        float4 w = Wrow[(size_t)d * 256];             // 1 KB/wave-instr, coalesced
        float kd = kk[d];                             // wave-uniform broadcast
        acc.x += kd * w.x; acc.y += kd * w.y;
        acc.z += kd * w.z; acc.w += kd * w.w;
    }
    union { __half2 h2[2]; uint2 u; } pk;
    pk.h2[0] = __floats2half2_rn(acc.x, acc.y);
    pk.h2[1] = __floats2half2_rn(acc.z, acc.w);
    *(uint2*)(wqk + (size_t)(b * 16 + h) * 1024 + t * 4) = pk.u;
}

// ---------------- Kernel C: att via MFMA + sigmoid gate + out -------------
// grid (128, 16): x = 16-row tile, y = batch. 256 threads = 4 waves, ALL on
// the SAME 16-row tile; wave w owns K-quarter [w*256, w*256+256) (8 chunks).
//
// Round-4 post-mortem: VGPR=36 proved LLVM collapsed the 4-slot rotation to
// just-in-time loads (2.5 TB/s = ~4KB/CU in flight by Little's law, vs the
// harness fillBuffer hitting 6.47 TB/s in the same profile). Fix: each wave
// BURST-ISSUES all 24 loads of its K-quarter first (96 VGPR of live results
// -- regalloc cannot coalesce: every load precedes every use), then
// sched_barrier(0) pins the boundary so the machine scheduler cannot sink
// loads into the compute phase. K-split also doubles the grid: 8192 waves,
// 16 resident waves/CU at VGPR<=128 -> ~hundreds of KB/CU in flight.
// Partial accs combine via padded LDS; broadcast-gate epilogue as before.
__global__ __launch_bounds__(256, 4) void att_kernel(
    const float* __restrict__ emb1, const float* __restrict__ ws,
    float* __restrict__ out)
{
    const int b    = blockIdx.y;
    const int t    = threadIdx.x;
    const int w    = t >> 6;
    const int lane = t & 63;
    const int q    = lane >> 4;        // quarter 0..3
    const int m    = lane & 15;        // row-in-tile (A) / head (B,D)

    const int row0 = blockIdx.x * 16;
    const int c0   = w * 8;            // this wave's first K-chunk

    const float*    vvec  = ws + 16384 + b * 1024;
    const float*    attbp = ws + 32768 + b * 16;
    const _Float16* wqk   = (const _Float16*)((const char*)ws + 132096)
                          + (size_t)b * 16384;

    const float*    Ap = emb1 + ((size_t)b * 2048 + row0 + m) * 1024 + q * 8;
    const _Float16* Bp = wqk + m * 1024 + q * 8;

    // ---- burst: issue ALL 24 loads of this wave's K-quarter ----
    f4v A0[8], A1[8];
    h8v Bf[8];
    #pragma unroll
    for (int i = 0; i < 8; ++i) {
        const float* ap = Ap + (c0 + i) * 32;
        A0[i] = *(const f4v*)(ap);
        A1[i] = *(const f4v*)(ap + 4);
        Bf[i] = *(const h8v*)(Bp + (c0 + i) * 32);
    }
    __builtin_amdgcn_sched_barrier(0);   // nothing crosses: loads stay hoisted

    // ---- compute: 8 MFMAs over K=256 ----
    f4v acc = {0.f, 0.f, 0.f, 0.f};
    #pragma unroll
    for (int i = 0; i < 8; ++i) {
        f4v a0 = A0[i], a1 = A1[i];
        h8v af;
        af[0] = (_Float16)a0[0]; af[1] = (_Float16)a0[1];
        af[2] = (_Float16)a0[2]; af[3] = (_Float16)a0[3];
        af[4] = (_Float16)a1[0]; af[5] = (_Float16)a1[1];
        af[6] = (_Float16)a1[2]; af[7] = (_Float16)a1[3];
        acc = __builtin_amdgcn_mfma_f32_16x16x32_f16(af, Bf[i], acc, 0, 0, 0);
    }

    // ---- combine K-quarter partials + gates (padded LDS, conflict-light) --
    __shared__ float sacc[4][16 * 17];
    __shared__ float sg[16 * 17];
    {
        float* sa = sacc[w];
        #pragma unroll
        for (int j = 0; j < 4; ++j)
            sa[(q * 4 + j) * 17 + m] = acc[j];       // row q*4+j, head m
    }
    __syncthreads();
    {
        const int r = t >> 4, h = t & 15;            // 256 threads = 256 (r,h)
        float s = sacc[0][r * 17 + h] + sacc[1][r * 17 + h]
                + sacc[2][r * 17 + h] + sacc[3][r * 17 + h] + attbp[h];
        sg[r * 17 + h] = 1.0f / (1.0f + __expf(-s));
    }
    __syncthreads();

    // ---- store 16 rows x 1024 cols, split across 4 waves (4 rows each) ----
    f4v vv[4];
    #pragma unroll
    for (int s = 0; s < 4; ++s)
        vv[s] = *(const f4v*)(vvec + s * 256 + lane * 4);

    float* Ob = out + ((size_t)b * 2048 + row0) * 1024 + lane * 4;
    #pragma unroll
    for (int k = 0; k < 4; ++k) {
        const int r = w * 4 + k;
        #pragma unroll
        for (int s = 0; s < 4; ++s) {
            // col = s*256 + lane*4  ->  head = s*4 + q
            float gg = sg[r * 17 + s * 4 + q];       // broadcast within quarter
            f4v o = gg * vv[s];
            __builtin_nontemporal_store(o, (f4v*)(Ob + (size_t)r * 1024 + s * 256));
        }
    }
}

extern "C" void kernel_launch(void* const* d_in, const int* in_sizes, int n_in,
                              void* d_out, int out_size, void* d_ws, size_t ws_size,
                              hipStream_t stream) {
    const float* emb1 = (const float*)d_in[0];
    const float* emb2 = (const float*)d_in[1];
    const float* Wq   = (const float*)d_in[2];
    const float* bq   = (const float*)d_in[3];
    const float* Wk   = (const float*)d_in[4];
    const float* bk   = (const float*)d_in[5];
    const float* Wv   = (const float*)d_in[6];
    const float* bv   = (const float*)d_in[7];
    float* out = (float*)d_out;
    float* ws  = (float*)d_ws;

    kv_kernel  <<<dim3(256, 2),  256, 0, stream>>>(emb2, Wk, bk, Wv, bv, ws);
    fold_kernel<<<dim3(16, 16),  256, 0, stream>>>(Wq, bq, ws);
    att_kernel <<<dim3(128, 16), 256, 0, stream>>>(emb1, ws, out);
}